// Round 4
// baseline (249.582 us; speedup 1.0000x reference)
//
#include <hip/hip_runtime.h>

// Problem constants (match reference)
#define BB 8
#define CC 3
#define HH 1024
#define WW 1024
#define NS 15728        // int(1024*1024*0.015)
#define NG (NS / 4)     // 3932 int4 groups (NS % 4 == 0)

// Gaussian 5-tap, sigma=1.5, normalized
#define G0 0.1200784f
#define G1 0.2338808f
#define G2 0.2920816f

// ---------------------------------------------------------------------------
// Kernel 1: snow boxes -> per-batch bitmask [B][H][W/32], built per 32-col
// stripe in LDS (1 word/row, 4 KiB). 256 blocks (32 stripes x 8 batches) so
// every CU gets work. Spots are scanned as int4 (4 spots per 3 loads) with a
// one-group-ahead prefetch -> the scan is MLP-rich instead of a latency chain.
// No memset needed: every word of mbits is written by exactly one block.
// ---------------------------------------------------------------------------
#define NSTRIPE 32

__global__ __launch_bounds__(256) void snow_mask_kernel(
    const int* __restrict__ ys, const int* __restrict__ xs,
    const int* __restrict__ rs, unsigned int* __restrict__ mbits) {
  __shared__ unsigned int lm[HH];
  const int b = blockIdx.y;
  const int sx0 = blockIdx.x << 5;  // 32-col stripe
  const int tid = threadIdx.x;

  for (int i = tid; i < HH; i += 256) lm[i] = 0u;
  __syncthreads();

  const int4* __restrict__ y4 = (const int4*)(ys + b * NS);
  const int4* __restrict__ x4 = (const int4*)(xs + b * NS);
  const int4* __restrict__ r4 = (const int4*)(rs + b * NS);

  auto spot = [&](int y, int x, int r) {
    r += 1;  // radius in {1,2,3}
    int x0 = max(x - r, sx0), x1 = min(x + r, sx0 + 31);
    if (x0 > x1) return;  // box misses this stripe (~97% reject)
    int y0 = max(y - r, 0), y1 = min(y + r, HH - 1);
    unsigned m = (0xFFFFFFFFu << (x0 & 31)) & (0xFFFFFFFFu >> (31 - (x1 & 31)));
    for (int py = y0; py <= y1; ++py) atomicOr(&lm[py], m);
  };

  int g = tid;
  int4 Y = {0, 0, 0, 0}, X = {0, 0, 0, 0}, R = {0, 0, 0, 0};
  bool have = g < NG;
  if (have) { Y = y4[g]; X = x4[g]; R = r4[g]; }
  while (have) {
    int gn = g + 256;
    int4 Yn = {0, 0, 0, 0}, Xn = {0, 0, 0, 0}, Rn = {0, 0, 0, 0};
    bool haven = gn < NG;
    if (haven) { Yn = y4[gn]; Xn = x4[gn]; Rn = r4[gn]; }  // prefetch
    spot(Y.x, X.x, R.x);
    spot(Y.y, X.y, R.y);
    spot(Y.z, X.z, R.z);
    spot(Y.w, X.w, R.w);
    g = gn; Y = Yn; X = Xn; R = Rn; have = haven;
  }
  __syncthreads();

  unsigned int* dst = mbits + ((unsigned)(b * HH) << 5) + blockIdx.x;
  for (int i = tid; i < HH; i += 256) dst[i << 5] = lm[i];
}

// ---------------------------------------------------------------------------
// Kernel 2: masked-fill (0.95) + separable 5x5 Gaussian + clip, fused.
// Register sliding window, no LDS/barriers. Thread owns 4 cols, slides 8
// rows (RROWS=8 -> 3072 blocks = 8 blocks/CU = 32 waves/CU: the kernel is
// latency-bound with ~1 row in flight per wave [VGPR=40 shows the compiler
// sank the pipeline], so we buy concurrency with occupancy instead).
// Per row: B float4 (own cols) + L/R float2 halo + 2 mask words.
// ---------------------------------------------------------------------------
#define RROWS 8

struct Row {
  float4 B;      // cols col..col+3
  float2 L;      // cols col-2,col-1 (clamped)
  float2 R;      // cols col+4,col+5 (clamped)
  unsigned m0, m1;
};

__global__ __launch_bounds__(256, 8) void snow_blur_kernel(
    const float* __restrict__ x, const unsigned int* __restrict__ mbits,
    float* __restrict__ out) {
  const int bz = blockIdx.y;        // b*CC + c
  const int b = bz / CC;
  const int gy0 = blockIdx.x * RROWS;
  const int tid = threadIdx.x;
  const int col = tid << 2;         // block spans full row width

  const float* __restrict__ xp = x + (size_t)bz * (HH * WW);
  const unsigned int* __restrict__ mb = mbits + ((unsigned)(b * HH) << 5);

  // loop-invariant per-lane geometry
  const int cL = max(col - 2, 0);
  const int cR = min(col + 4, WW - 2);
  const unsigned loob = (col == 0) ? 16u : 0u;
  const unsigned roob = (col == WW - 4) ? 16u : 0u;
  const int w = cL >> 5;                  // word holding col-2 (clamped)
  const int w2 = min(w + 1, 31);
  const int bpL = cL - (w << 5);          // bit pos of col-2 in 64-bit window
  const int bpB = col - (w << 5);         // bit pos of col   (may be >=32)
  const int bpR = col + 4 - (w << 5);     // bit pos of col+4 (<=36)

  auto loadrow = [&](int gy, Row& rw) {
    int gyc = min(max(gy, 0), HH - 1);
    const float* rp = xp + ((size_t)gyc << 10);
    const unsigned* mrow = mb + (gyc << 5);
    rw.B = *(const float4*)(rp + col);
    rw.L = *(const float2*)(rp + cL);
    rw.R = *(const float2*)(rp + cR);
    rw.m0 = mrow[w];
    rw.m1 = mrow[w2];
  };

  // consume one staged row -> horizontal 5-tap for 4 cols
  auto consume = [&](const Row& rw, unsigned ro) {
    unsigned long long mw =
        (unsigned long long)rw.m0 | ((unsigned long long)rw.m1 << 32);
    unsigned bL = ((unsigned)(mw >> bpL) & 3u) | ro | loob;
    unsigned bB = ((unsigned)(mw >> bpB) & 0xFu) | ro;
    unsigned bR = ((unsigned)(mw >> bpR) & 3u) | ro | roob;
    float2 fL;
    fL.x = (bL & 1u) ? 0.95f : rw.L.x;
    fL.y = (bL & 2u) ? 0.95f : rw.L.y;
    if (bL & 16u) { fL.x = 0.f; fL.y = 0.f; }
    float4 fB;
    fB.x = (bB & 1u) ? 0.95f : rw.B.x;
    fB.y = (bB & 2u) ? 0.95f : rw.B.y;
    fB.z = (bB & 4u) ? 0.95f : rw.B.z;
    fB.w = (bB & 8u) ? 0.95f : rw.B.w;
    if (bB & 16u) { fB.x = 0.f; fB.y = 0.f; fB.z = 0.f; fB.w = 0.f; }
    float2 fR;
    fR.x = (bR & 1u) ? 0.95f : rw.R.x;
    fR.y = (bR & 2u) ? 0.95f : rw.R.y;
    if (bR & 16u) { fR.x = 0.f; fR.y = 0.f; }
    float4 h;
    h.x = G0 * (fL.x + fB.z) + G1 * (fL.y + fB.y) + G2 * fB.x;
    h.y = G0 * (fL.y + fB.w) + G1 * (fB.x + fB.z) + G2 * fB.y;
    h.z = G0 * (fB.x + fR.x) + G1 * (fB.y + fB.w) + G2 * fB.z;
    h.w = G0 * (fB.y + fR.y) + G1 * (fB.z + fR.x) + G2 * fB.w;
    return h;
  };

  auto rof = [&](int gy) { return (gy < 0 || gy >= HH) ? 16u : 0u; };

  // ---- prologue: issue ALL 7 rows' loads before any consumption ----
  Row p0, p1, p2, p3, s0, s1, s2;
  loadrow(gy0 - 2, p0);
  loadrow(gy0 - 1, p1);
  loadrow(gy0 + 0, p2);
  loadrow(gy0 + 1, p3);
  loadrow(gy0 + 2, s0);
  loadrow(gy0 + 3, s1);
  loadrow(gy0 + 4, s2);
  float4 h0 = consume(p0, rof(gy0 - 2));
  float4 h1 = consume(p1, rof(gy0 - 1));
  float4 h2 = consume(p2, 0u);   // gy0..gy0+1 always in range
  float4 h3 = consume(p3, 0u);

  float* op = out + (size_t)bz * (HH * WW) + ((size_t)gy0 << 10) + col;
#pragma unroll
  for (int k = 0; k < RROWS; ++k) {
    Row nr{};
    if (k < RROWS - 3) loadrow(gy0 + 5 + k, nr);   // static guard (unrolled)

    float4 h4 = consume(s0, rof(gy0 + 2 + k));

    float4 s;
    s.x = G0 * (h0.x + h4.x) + G1 * (h1.x + h3.x) + G2 * h2.x;
    s.y = G0 * (h0.y + h4.y) + G1 * (h1.y + h3.y) + G2 * h2.y;
    s.z = G0 * (h0.z + h4.z) + G1 * (h1.z + h3.z) + G2 * h2.z;
    s.w = G0 * (h0.w + h4.w) + G1 * (h1.w + h3.w) + G2 * h2.w;
    s.x = fminf(fmaxf(s.x, 0.f), 1.f);
    s.y = fminf(fmaxf(s.y, 0.f), 1.f);
    s.z = fminf(fmaxf(s.z, 0.f), 1.f);
    s.w = fminf(fmaxf(s.w, 0.f), 1.f);
    *(float4*)op = s;
    op += WW;

    s0 = s1; s1 = s2; s2 = nr;
    h0 = h1; h1 = h2; h2 = h3; h3 = h4;
  }
}

// ---------------------------------------------------------------------------
extern "C" void kernel_launch(void* const* d_in, const int* in_sizes, int n_in,
                              void* d_out, int out_size, void* d_ws, size_t ws_size,
                              hipStream_t stream) {
  const float* x = (const float*)d_in[0];
  const int* ys = (const int*)d_in[1];
  const int* xs = (const int*)d_in[2];
  const int* rs = (const int*)d_in[3];
  float* out = (float*)d_out;

  unsigned int* mbits = (unsigned int*)d_ws;  // B*H*W/8 = 1 MiB
  // no memset: mask kernel fully overwrites every word of mbits

  dim3 mgrid(NSTRIPE, BB);
  snow_mask_kernel<<<mgrid, 256, 0, stream>>>(ys, xs, rs, mbits);

  dim3 grid(HH / RROWS, BB * CC);
  snow_blur_kernel<<<grid, 256, 0, stream>>>(x, mbits, out);
}

// Round 5
// 206.853 us; speedup vs baseline: 1.2066x; 1.2066x over previous
//
#include <hip/hip_runtime.h>

// Problem constants (match reference)
#define BB 8
#define CC 3
#define HH 1024
#define WW 1024
#define NS 15728        // int(1024*1024*0.015)
#define NG (NS / 4)     // 3932 int4 groups (NS % 4 == 0)

// Gaussian 5-tap, sigma=1.5, normalized
#define G0 0.1200784f
#define G1 0.2338808f
#define G2 0.2920816f

// ---------------------------------------------------------------------------
// Kernel 1: snow boxes -> per-batch bitmask [B][H][W/32], built per 32-col
// stripe in LDS (1 word/row, 4 KiB). 256 blocks (32 stripes x 8 batches).
// Spots scanned as int4 with one-group-ahead prefetch. No memset needed.
// ---------------------------------------------------------------------------
#define NSTRIPE 32

__global__ __launch_bounds__(256) void snow_mask_kernel(
    const int* __restrict__ ys, const int* __restrict__ xs,
    const int* __restrict__ rs, unsigned int* __restrict__ mbits) {
  __shared__ unsigned int lm[HH];
  const int b = blockIdx.y;
  const int sx0 = blockIdx.x << 5;  // 32-col stripe
  const int tid = threadIdx.x;

  for (int i = tid; i < HH; i += 256) lm[i] = 0u;
  __syncthreads();

  const int4* __restrict__ y4 = (const int4*)(ys + b * NS);
  const int4* __restrict__ x4 = (const int4*)(xs + b * NS);
  const int4* __restrict__ r4 = (const int4*)(rs + b * NS);

  auto spot = [&](int y, int x, int r) {
    r += 1;  // radius in {1,2,3}
    int x0 = max(x - r, sx0), x1 = min(x + r, sx0 + 31);
    if (x0 > x1) return;  // box misses this stripe (~97% reject)
    int y0 = max(y - r, 0), y1 = min(y + r, HH - 1);
    unsigned m = (0xFFFFFFFFu << (x0 & 31)) & (0xFFFFFFFFu >> (31 - (x1 & 31)));
    for (int py = y0; py <= y1; ++py) atomicOr(&lm[py], m);
  };

  int g = tid;
  int4 Y = {0, 0, 0, 0}, X = {0, 0, 0, 0}, R = {0, 0, 0, 0};
  bool have = g < NG;
  if (have) { Y = y4[g]; X = x4[g]; R = r4[g]; }
  while (have) {
    int gn = g + 256;
    int4 Yn = {0, 0, 0, 0}, Xn = {0, 0, 0, 0}, Rn = {0, 0, 0, 0};
    bool haven = gn < NG;
    if (haven) { Yn = y4[gn]; Xn = x4[gn]; Rn = r4[gn]; }  // prefetch
    spot(Y.x, X.x, R.x);
    spot(Y.y, X.y, R.y);
    spot(Y.z, X.z, R.z);
    spot(Y.w, X.w, R.w);
    g = gn; Y = Yn; X = Xn; R = Rn; have = haven;
  }
  __syncthreads();

  unsigned int* dst = mbits + ((unsigned)(b * HH) << 5) + blockIdx.x;
  for (int i = tid; i < HH; i += 256) dst[i << 5] = lm[i];
}

// ---------------------------------------------------------------------------
// Kernel 2: masked-fill (0.95) + separable 5x5 Gaussian + clip, fused.
// Register sliding window, RROWS=16 (traffic-optimal tiling: round-4 showed
// RROWS=8 doubles HBM traffic via halo/L3 thrash). The round-3 version
// compiled to VGPR=40: the compiler SANK the pipelined loads to their
// consumes, leaving ~1 row in flight (latency-bound, VALUBusy 22%).
// Fix: __builtin_amdgcn_sched_barrier(0) after every load-issue block pins
// the loads above it -> 3 rows in flight per wave survive codegen.
// ---------------------------------------------------------------------------
#define RROWS 16

struct Row {
  float4 B;      // cols col..col+3
  float2 L;      // cols col-2,col-1 (clamped)
  float2 R;      // cols col+4,col+5 (clamped)
  unsigned m0, m1;
};

__global__ __launch_bounds__(256, 4) void snow_blur_kernel(
    const float* __restrict__ x, const unsigned int* __restrict__ mbits,
    float* __restrict__ out) {
  const int bz = blockIdx.y;        // b*CC + c
  const int b = bz / CC;
  const int gy0 = blockIdx.x * RROWS;
  const int tid = threadIdx.x;
  const int col = tid << 2;         // block spans full row width

  const float* __restrict__ xp = x + (size_t)bz * (HH * WW);
  const unsigned int* __restrict__ mb = mbits + ((unsigned)(b * HH) << 5);

  // loop-invariant per-lane geometry
  const int cL = max(col - 2, 0);
  const int cR = min(col + 4, WW - 2);
  const unsigned loob = (col == 0) ? 16u : 0u;
  const unsigned roob = (col == WW - 4) ? 16u : 0u;
  const int w = cL >> 5;                  // word holding col-2 (clamped)
  const int w2 = min(w + 1, 31);
  const int bpL = cL - (w << 5);          // bit pos of col-2 in 64-bit window
  const int bpB = col - (w << 5);         // bit pos of col   (may be >=32)
  const int bpR = col + 4 - (w << 5);     // bit pos of col+4 (<=36)

  auto loadrow = [&](int gy, Row& rw) {
    int gyc = min(max(gy, 0), HH - 1);
    const float* rp = xp + ((size_t)gyc << 10);
    const unsigned* mrow = mb + (gyc << 5);
    rw.B = *(const float4*)(rp + col);
    rw.L = *(const float2*)(rp + cL);
    rw.R = *(const float2*)(rp + cR);
    rw.m0 = mrow[w];
    rw.m1 = mrow[w2];
  };

  // consume one staged row -> horizontal 5-tap for 4 cols
  auto consume = [&](const Row& rw, unsigned ro) {
    unsigned long long mw =
        (unsigned long long)rw.m0 | ((unsigned long long)rw.m1 << 32);
    unsigned bL = ((unsigned)(mw >> bpL) & 3u) | ro | loob;
    unsigned bB = ((unsigned)(mw >> bpB) & 0xFu) | ro;
    unsigned bR = ((unsigned)(mw >> bpR) & 3u) | ro | roob;
    float2 fL;
    fL.x = (bL & 1u) ? 0.95f : rw.L.x;
    fL.y = (bL & 2u) ? 0.95f : rw.L.y;
    if (bL & 16u) { fL.x = 0.f; fL.y = 0.f; }
    float4 fB;
    fB.x = (bB & 1u) ? 0.95f : rw.B.x;
    fB.y = (bB & 2u) ? 0.95f : rw.B.y;
    fB.z = (bB & 4u) ? 0.95f : rw.B.z;
    fB.w = (bB & 8u) ? 0.95f : rw.B.w;
    if (bB & 16u) { fB.x = 0.f; fB.y = 0.f; fB.z = 0.f; fB.w = 0.f; }
    float2 fR;
    fR.x = (bR & 1u) ? 0.95f : rw.R.x;
    fR.y = (bR & 2u) ? 0.95f : rw.R.y;
    if (bR & 16u) { fR.x = 0.f; fR.y = 0.f; }
    float4 h;
    h.x = G0 * (fL.x + fB.z) + G1 * (fL.y + fB.y) + G2 * fB.x;
    h.y = G0 * (fL.y + fB.w) + G1 * (fB.x + fB.z) + G2 * fB.y;
    h.z = G0 * (fB.x + fR.x) + G1 * (fB.y + fB.w) + G2 * fB.z;
    h.w = G0 * (fB.y + fR.y) + G1 * (fB.z + fR.x) + G2 * fB.w;
    return h;
  };

  auto rof = [&](int gy) { return (gy < 0 || gy >= HH) ? 16u : 0u; };

  // ---- prologue: issue ALL 7 rows' loads before any consumption ----
  Row p0, p1, p2, p3, s0, s1, s2;
  loadrow(gy0 - 2, p0);
  loadrow(gy0 - 1, p1);
  loadrow(gy0 + 0, p2);
  loadrow(gy0 + 1, p3);
  loadrow(gy0 + 2, s0);
  loadrow(gy0 + 3, s1);
  loadrow(gy0 + 4, s2);
  __builtin_amdgcn_sched_barrier(0);   // pin: loads may not sink below here
  float4 h0 = consume(p0, rof(gy0 - 2));
  float4 h1 = consume(p1, rof(gy0 - 1));
  float4 h2 = consume(p2, 0u);   // gy0..gy0+1 always in range
  float4 h3 = consume(p3, 0u);

  float* op = out + (size_t)bz * (HH * WW) + ((size_t)gy0 << 10) + col;
#pragma unroll
  for (int k = 0; k < RROWS; ++k) {
    Row nr{};
    if (k < RROWS - 3) {
      loadrow(gy0 + 5 + k, nr);        // static guard (unrolled)
      __builtin_amdgcn_sched_barrier(0);  // keep this issue ahead of compute
    }

    float4 h4 = consume(s0, rof(gy0 + 2 + k));

    float4 s;
    s.x = G0 * (h0.x + h4.x) + G1 * (h1.x + h3.x) + G2 * h2.x;
    s.y = G0 * (h0.y + h4.y) + G1 * (h1.y + h3.y) + G2 * h2.y;
    s.z = G0 * (h0.z + h4.z) + G1 * (h1.z + h3.z) + G2 * h2.z;
    s.w = G0 * (h0.w + h4.w) + G1 * (h1.w + h3.w) + G2 * h2.w;
    s.x = fminf(fmaxf(s.x, 0.f), 1.f);
    s.y = fminf(fmaxf(s.y, 0.f), 1.f);
    s.z = fminf(fmaxf(s.z, 0.f), 1.f);
    s.w = fminf(fmaxf(s.w, 0.f), 1.f);
    *(float4*)op = s;
    op += WW;

    s0 = s1; s1 = s2; s2 = nr;
    h0 = h1; h1 = h2; h2 = h3; h3 = h4;
  }
}

// ---------------------------------------------------------------------------
extern "C" void kernel_launch(void* const* d_in, const int* in_sizes, int n_in,
                              void* d_out, int out_size, void* d_ws, size_t ws_size,
                              hipStream_t stream) {
  const float* x = (const float*)d_in[0];
  const int* ys = (const int*)d_in[1];
  const int* xs = (const int*)d_in[2];
  const int* rs = (const int*)d_in[3];
  float* out = (float*)d_out;

  unsigned int* mbits = (unsigned int*)d_ws;  // B*H*W/8 = 1 MiB
  // no memset: mask kernel fully overwrites every word of mbits

  dim3 mgrid(NSTRIPE, BB);
  snow_mask_kernel<<<mgrid, 256, 0, stream>>>(ys, xs, rs, mbits);

  dim3 grid(HH / RROWS, BB * CC);
  snow_blur_kernel<<<grid, 256, 0, stream>>>(x, mbits, out);
}

// Round 6
// 205.180 us; speedup vs baseline: 1.2164x; 1.0082x over previous
//
#include <hip/hip_runtime.h>

// Problem constants (match reference)
#define BB 8
#define CC 3
#define HH 1024
#define WW 1024
#define NS 15728        // int(1024*1024*0.015)
#define NG (NS / 4)     // 3932 int4 groups (NS % 4 == 0)

// Gaussian 5-tap, sigma=1.5, normalized
#define G0 0.1200784f
#define G1 0.2338808f
#define G2 0.2920816f

// ---------------------------------------------------------------------------
// Kernel 1: snow boxes -> per-batch bitmask [B][H][W/32], built per 32-col
// stripe in LDS (1 word/row, 4 KiB). 256 blocks (32 stripes x 8 batches).
// Spots scanned as int4 with one-group-ahead prefetch. No memset needed.
// (verified ~5 us in rounds 3-5; unchanged)
// ---------------------------------------------------------------------------
#define NSTRIPE 32

__global__ __launch_bounds__(256) void snow_mask_kernel(
    const int* __restrict__ ys, const int* __restrict__ xs,
    const int* __restrict__ rs, unsigned int* __restrict__ mbits) {
  __shared__ unsigned int lm[HH];
  const int b = blockIdx.y;
  const int sx0 = blockIdx.x << 5;  // 32-col stripe
  const int tid = threadIdx.x;

  for (int i = tid; i < HH; i += 256) lm[i] = 0u;
  __syncthreads();

  const int4* __restrict__ y4 = (const int4*)(ys + b * NS);
  const int4* __restrict__ x4 = (const int4*)(xs + b * NS);
  const int4* __restrict__ r4 = (const int4*)(rs + b * NS);

  auto spot = [&](int y, int x, int r) {
    r += 1;  // radius in {1,2,3}
    int x0 = max(x - r, sx0), x1 = min(x + r, sx0 + 31);
    if (x0 > x1) return;  // box misses this stripe (~97% reject)
    int y0 = max(y - r, 0), y1 = min(y + r, HH - 1);
    unsigned m = (0xFFFFFFFFu << (x0 & 31)) & (0xFFFFFFFFu >> (31 - (x1 & 31)));
    for (int py = y0; py <= y1; ++py) atomicOr(&lm[py], m);
  };

  int g = tid;
  int4 Y = {0, 0, 0, 0}, X = {0, 0, 0, 0}, R = {0, 0, 0, 0};
  bool have = g < NG;
  if (have) { Y = y4[g]; X = x4[g]; R = r4[g]; }
  while (have) {
    int gn = g + 256;
    int4 Yn = {0, 0, 0, 0}, Xn = {0, 0, 0, 0}, Rn = {0, 0, 0, 0};
    bool haven = gn < NG;
    if (haven) { Yn = y4[gn]; Xn = x4[gn]; Rn = r4[gn]; }  // prefetch
    spot(Y.x, X.x, R.x);
    spot(Y.y, X.y, R.y);
    spot(Y.z, X.z, R.z);
    spot(Y.w, X.w, R.w);
    g = gn; Y = Yn; X = Xn; R = Rn; have = haven;
  }
  __syncthreads();

  unsigned int* dst = mbits + ((unsigned)(b * HH) << 5) + blockIdx.x;
  for (int i = tid; i < HH; i += 256) dst[i << 5] = lm[i];
}

// ---------------------------------------------------------------------------
// Kernel 2: masked-fill (0.95) + separable 5x5 Gaussian + clip, fused.
// RROWS=16 register sliding window. Rounds 3/5 proved the compiler serializes
// the 5 loads/row (sinks each to its consume; ~4900 cy/row). Fix: inline-asm
// loads (opaque -> cannot be sunk) + hand-counted s_waitcnt vmcnt(N)
// (counts: 5 asm loads/row + 1 compiler store/iter, stores confined between
// memory-clobbered waits) + sched_barrier(0) after each wait (rule 18).
// Steady state: 4 rows (20 loads) in flight per wave.
// ---------------------------------------------------------------------------
#define RROWS 16

struct Row {
  float4 B;      // cols col..col+3
  float2 L;      // cols col-2,col-1 (clamped)
  float2 R;      // cols col+4,col+5 (clamped)
  unsigned m0, m1;
};

template <int N>
__device__ __forceinline__ void wait_vmcnt() {
  asm volatile("s_waitcnt vmcnt(%0)" ::"n"(N) : "memory");
  __builtin_amdgcn_sched_barrier(0);
}

__device__ __forceinline__ void ld4(const float* p, float4& d) {
  asm volatile("global_load_dwordx4 %0, %1, off" : "=v"(d) : "v"(p));
}
__device__ __forceinline__ void ld2(const float* p, float2& d) {
  asm volatile("global_load_dwordx2 %0, %1, off" : "=v"(d) : "v"(p));
}
__device__ __forceinline__ void ld1(const unsigned* p, unsigned& d) {
  asm volatile("global_load_dword %0, %1, off" : "=v"(d) : "v"(p));
}

__global__ __launch_bounds__(256, 4) void snow_blur_kernel(
    const float* __restrict__ x, const unsigned int* __restrict__ mbits,
    float* __restrict__ out) {
  const int bz = blockIdx.y;        // b*CC + c
  const int b = bz / CC;
  const int gy0 = blockIdx.x * RROWS;
  const int tid = threadIdx.x;
  const int col = tid << 2;         // block spans full row width

  const float* __restrict__ xp = x + (size_t)bz * (HH * WW);
  const unsigned int* __restrict__ mb = mbits + ((unsigned)(b * HH) << 5);

  // loop-invariant per-lane geometry
  const int cL = max(col - 2, 0);
  const int cR = min(col + 4, WW - 2);
  const unsigned loob = (col == 0) ? 16u : 0u;
  const unsigned roob = (col == WW - 4) ? 16u : 0u;
  const int w = cL >> 5;                  // word holding col-2 (clamped)
  const int w2 = min(w + 1, 31);
  const int bpL = cL - (w << 5);          // bit pos of col-2 in 64-bit window
  const int bpB = col - (w << 5);         // bit pos of col   (may be >=32)
  const int bpR = col + 4 - (w << 5);     // bit pos of col+4 (<=36)

  // issue one row's 5 loads (asm: cannot be sunk or serialized by compiler)
  auto issue = [&](int gy, Row& rw) {
    int gyc = min(max(gy, 0), HH - 1);
    const float* rp = xp + ((size_t)gyc << 10);
    const unsigned* mrow = mb + (gyc << 5);
    ld4(rp + col, rw.B);
    ld2(rp + cL, rw.L);
    ld2(rp + cR, rw.R);
    ld1(mrow + w, rw.m0);
    ld1(mrow + w2, rw.m1);
  };

  // consume one staged row -> horizontal 5-tap for 4 cols
  auto consume = [&](const Row& rw, unsigned ro) {
    unsigned long long mw =
        (unsigned long long)rw.m0 | ((unsigned long long)rw.m1 << 32);
    unsigned bL = ((unsigned)(mw >> bpL) & 3u) | ro | loob;
    unsigned bB = ((unsigned)(mw >> bpB) & 0xFu) | ro;
    unsigned bR = ((unsigned)(mw >> bpR) & 3u) | ro | roob;
    float2 fL;
    fL.x = (bL & 1u) ? 0.95f : rw.L.x;
    fL.y = (bL & 2u) ? 0.95f : rw.L.y;
    if (bL & 16u) { fL.x = 0.f; fL.y = 0.f; }
    float4 fB;
    fB.x = (bB & 1u) ? 0.95f : rw.B.x;
    fB.y = (bB & 2u) ? 0.95f : rw.B.y;
    fB.z = (bB & 4u) ? 0.95f : rw.B.z;
    fB.w = (bB & 8u) ? 0.95f : rw.B.w;
    if (bB & 16u) { fB.x = 0.f; fB.y = 0.f; fB.z = 0.f; fB.w = 0.f; }
    float2 fR;
    fR.x = (bR & 1u) ? 0.95f : rw.R.x;
    fR.y = (bR & 2u) ? 0.95f : rw.R.y;
    if (bR & 16u) { fR.x = 0.f; fR.y = 0.f; }
    float4 h;
    h.x = G0 * (fL.x + fB.z) + G1 * (fL.y + fB.y) + G2 * fB.x;
    h.y = G0 * (fL.y + fB.w) + G1 * (fB.x + fB.z) + G2 * fB.y;
    h.z = G0 * (fB.x + fR.x) + G1 * (fB.y + fB.w) + G2 * fB.z;
    h.w = G0 * (fB.y + fR.y) + G1 * (fB.z + fR.x) + G2 * fB.w;
    return h;
  };

  auto rof = [&](int gy) { return (gy < 0 || gy >= HH) ? 16u : 0u; };

  // ---- prologue: issue all 7 rows (35 loads), then counted consumes ----
  Row ra, rb, rc, rd, s0, s1, s2;
  issue(gy0 - 2, ra);
  issue(gy0 - 1, rb);
  issue(gy0 + 0, rc);
  issue(gy0 + 1, rd);
  issue(gy0 + 2, s0);
  issue(gy0 + 3, s1);
  issue(gy0 + 4, s2);
  wait_vmcnt<30>();
  float4 h0 = consume(ra, rof(gy0 - 2));
  wait_vmcnt<25>();
  float4 h1 = consume(rb, rof(gy0 - 1));
  wait_vmcnt<20>();
  float4 h2 = consume(rc, 0u);   // gy0..gy0+1 always in range
  wait_vmcnt<15>();
  float4 h3 = consume(rd, 0u);

  float* op = out + (size_t)bz * (HH * WW) + ((size_t)gy0 << 10) + col;

  // per-iter wait counts (loads=5/row, store=1/iter, statically derived):
  // k=0:15  k=1:16  k=2:17  k=3..12:18  k=13:13  k=14:8  k=15:3
#define STEP(K, WN)                                                     \
  {                                                                     \
    Row nr{};                                                           \
    if ((K) < RROWS - 3) issue(gy0 + 5 + (K), nr);                      \
    wait_vmcnt<WN>();                                                   \
    float4 h4 = consume(s0, rof(gy0 + 2 + (K)));                        \
    float4 sv;                                                          \
    sv.x = G0 * (h0.x + h4.x) + G1 * (h1.x + h3.x) + G2 * h2.x;         \
    sv.y = G0 * (h0.y + h4.y) + G1 * (h1.y + h3.y) + G2 * h2.y;         \
    sv.z = G0 * (h0.z + h4.z) + G1 * (h1.z + h3.z) + G2 * h2.z;         \
    sv.w = G0 * (h0.w + h4.w) + G1 * (h1.w + h3.w) + G2 * h2.w;         \
    sv.x = fminf(fmaxf(sv.x, 0.f), 1.f);                                \
    sv.y = fminf(fmaxf(sv.y, 0.f), 1.f);                                \
    sv.z = fminf(fmaxf(sv.z, 0.f), 1.f);                                \
    sv.w = fminf(fmaxf(sv.w, 0.f), 1.f);                                \
    *(float4*)op = sv;                                                  \
    op += WW;                                                           \
    s0 = s1; s1 = s2; s2 = nr;                                          \
    h0 = h1; h1 = h2; h2 = h3; h3 = h4;                                 \
  }

  STEP(0, 15)
  STEP(1, 16)
  STEP(2, 17)
  STEP(3, 18)
  STEP(4, 18)
  STEP(5, 18)
  STEP(6, 18)
  STEP(7, 18)
  STEP(8, 18)
  STEP(9, 18)
  STEP(10, 18)
  STEP(11, 18)
  STEP(12, 18)
  STEP(13, 13)
  STEP(14, 8)
  STEP(15, 3)
#undef STEP
}

// ---------------------------------------------------------------------------
extern "C" void kernel_launch(void* const* d_in, const int* in_sizes, int n_in,
                              void* d_out, int out_size, void* d_ws, size_t ws_size,
                              hipStream_t stream) {
  const float* x = (const float*)d_in[0];
  const int* ys = (const int*)d_in[1];
  const int* xs = (const int*)d_in[2];
  const int* rs = (const int*)d_in[3];
  float* out = (float*)d_out;

  unsigned int* mbits = (unsigned int*)d_ws;  // B*H*W/8 = 1 MiB
  // no memset: mask kernel fully overwrites every word of mbits

  dim3 mgrid(NSTRIPE, BB);
  snow_mask_kernel<<<mgrid, 256, 0, stream>>>(ys, xs, rs, mbits);

  dim3 grid(HH / RROWS, BB * CC);
  snow_blur_kernel<<<grid, 256, 0, stream>>>(x, mbits, out);
}